// Round 6
// baseline (464.086 us; speedup 1.0000x reference)
//
#include <hip/hip_runtime.h>

#define D_MODEL 1024
#define VOCAB   50257

// R4 structure (best so far): one block (256 thr = 4 waves) per row; wave w
// owns levels 4w..4w+3; 16 unconditional clamped-index float4 weight loads
// per wave chunk; 6-shfl reduce-scatter; lane-parallel log-sigmoid; LDS
// combine; plain store (idempotent -- safe to launch 5x).
// MEASUREMENT ROUND: kernel_launch launches this 5x back-to-back so the
// dispatch shows up in the top-5 rocprof table (it is otherwise shorter than
// the harness's ~123us poison fills). Cold (launch 1) vs warm (2-5)
// FETCH_SIZE/dur discriminates compulsory-HBM-bound vs fabric/latency-bound.
__global__ __launch_bounds__(256) void hs_kernel(
    const float* __restrict__ input,       // [B, D_MODEL]
    const float* __restrict__ W,           // [VOCAB-1, D_MODEL]
    const int*   __restrict__ path_nodes,  // [VOCAB, Dmax]
    const float* __restrict__ path_signs,  // [VOCAB, Dmax]
    const int*   __restrict__ target,      // [B]
    float*       __restrict__ out,         // [B]
    int Dmax)
{
    const int b    = blockIdx.x;
    const int tid  = threadIdx.x;
    const int lane = tid & 63;
    const int wave = tid >> 6;  // 0..3

    __shared__ int   s_nodes[64];
    __shared__ float s_signs[64];
    __shared__ float s_partial[4];

    const int t = target[b];
    for (int i = tid; i < Dmax; i += 256) {
        s_nodes[i] = path_nodes[t * Dmax + i];
        s_signs[i] = path_signs[t * Dmax + i];
    }
    __syncthreads();

    const float4* x4 = reinterpret_cast<const float4*>(input + (size_t)b * D_MODEL);
    const float4 x0 = x4[lane];
    const float4 x1 = x4[lane + 64];
    const float4 x2 = x4[lane + 128];
    const float4 x3 = x4[lane + 192];

    float acc = 0.0f;

    for (int k0 = wave * 4; k0 < Dmax; k0 += 16) {
        const float4* wp[4];
        #pragma unroll
        for (int j = 0; j < 4; ++j) {
            int k = k0 + j;
            if (k > Dmax - 1) k = Dmax - 1;
            wp[j] = reinterpret_cast<const float4*>(
                W + (size_t)s_nodes[k] * D_MODEL);
        }

        float v[4];
        #pragma unroll
        for (int j = 0; j < 4; ++j) {
            const float4 w0 = wp[j][lane];
            const float4 w1 = wp[j][lane + 64];
            const float4 w2 = wp[j][lane + 128];
            const float4 w3 = wp[j][lane + 192];
            v[j] = x0.x * w0.x + x0.y * w0.y + x0.z * w0.z + x0.w * w0.w
                 + x1.x * w1.x + x1.y * w1.y + x1.z * w1.z + x1.w * w1.w
                 + x2.x * w2.x + x2.y * w2.y + x2.z * w2.z + x2.w * w2.w
                 + x3.x * w3.x + x3.y * w3.y + x3.z * w3.z + x3.w * w3.w;
        }

        const bool b5 = (lane & 32) != 0;
        const bool b4 = (lane & 16) != 0;
        const float t0 = b5 ? v[0] : v[2];
        const float t1 = b5 ? v[1] : v[3];
        const float r0 = __shfl_xor(t0, 32);
        const float r1 = __shfl_xor(t1, 32);
        const float a  = (b5 ? v[2] : v[0]) + r0;
        const float c  = (b5 ? v[3] : v[1]) + r1;
        const float tt = b4 ? a : c;
        const float rr = __shfl_xor(tt, 16);
        float s = (b4 ? c : a) + rr;
        s += __shfl_xor(s, 8);
        s += __shfl_xor(s, 4);
        s += __shfl_xor(s, 2);
        s += __shfl_xor(s, 1);

        const int kk = k0 + ((lane >> 4) & 3);
        const float sgn = (kk < Dmax) ? s_signs[kk] : 0.0f;
        float term = 0.0f;
        if (sgn != 0.0f) {
            const float z = sgn * s;
            term = fminf(z, 0.0f) - log1pf(expf(-fabsf(z)));
        }
        term += __shfl_xor(term, 16);
        term += __shfl_xor(term, 32);
        acc += term;
    }

    if (lane == 0) s_partial[wave] = acc;
    __syncthreads();
    if (tid == 0)
        out[b] = s_partial[0] + s_partial[1] + s_partial[2] + s_partial[3];
}

extern "C" void kernel_launch(void* const* d_in, const int* in_sizes, int n_in,
                              void* d_out, int out_size, void* d_ws, size_t ws_size,
                              hipStream_t stream) {
    const float* input      = (const float*)d_in[0];
    const float* W          = (const float*)d_in[1];
    const int*   path_nodes = (const int*)d_in[2];
    const float* path_signs = (const float*)d_in[3];
    const int*   target     = (const int*)d_in[4];
    float*       out        = (float*)d_out;

    const int B    = in_sizes[4];
    const int Dmax = in_sizes[2] / VOCAB;

    // 5 identical idempotent launches: measurement round (see header comment).
    for (int rep = 0; rep < 5; ++rep) {
        hs_kernel<<<B, 256, 0, stream>>>(input, W, path_nodes, path_signs,
                                         target, out, Dmax);
    }
}

// Round 7
// 343.250 us; speedup vs baseline: 1.3520x; 1.3520x over previous
//
#include <hip/hip_runtime.h>

#define D_MODEL 1024
#define VOCAB   50257

// MEASUREMENT ROUND 2: R4 structure, but THREE in-kernel passes over the
// levels (pass r rotates each wave's level-group start by r*4 -> different
// expression trees, no CSE, identical math). Single dispatch now ~130-185us
// so it FINALLY enters the rocprof top-5 table and yields FETCH_SIZE /
// VALUBusy / Occupancy for the real kernel. Its FETCH_SIZE discriminates:
//   cold-LLC model: >=150 MB ; warm-LLC model: <60 MB.
__global__ __launch_bounds__(256) void hs_kernel(
    const float* __restrict__ input,       // [B, D_MODEL]
    const float* __restrict__ W,           // [VOCAB-1, D_MODEL]
    const int*   __restrict__ path_nodes,  // [VOCAB, Dmax]
    const float* __restrict__ path_signs,  // [VOCAB, Dmax]
    const int*   __restrict__ target,      // [B]
    float*       __restrict__ out,         // [B]
    int Dmax)
{
    const int b    = blockIdx.x;
    const int tid  = threadIdx.x;
    const int lane = tid & 63;
    const int wave = tid >> 6;  // 0..3

    __shared__ int   s_nodes[64];
    __shared__ float s_signs[64];
    __shared__ float s_partial[4];

    const int t = target[b];
    for (int i = tid; i < Dmax; i += 256) {
        s_nodes[i] = path_nodes[t * Dmax + i];
        s_signs[i] = path_signs[t * Dmax + i];
    }
    __syncthreads();

    const float4* x4 = reinterpret_cast<const float4*>(input + (size_t)b * D_MODEL);
    const float4 x0 = x4[lane];
    const float4 x1 = x4[lane + 64];
    const float4 x2 = x4[lane + 128];
    const float4 x3 = x4[lane + 192];

    for (int r = 0; r < 3; ++r) {
        float acc = 0.0f;

        for (int k0 = ((wave + r) & 3) * 4; k0 < Dmax; k0 += 16) {
            const float4* wp[4];
            #pragma unroll
            for (int j = 0; j < 4; ++j) {
                int k = k0 + j;
                if (k > Dmax - 1) k = Dmax - 1;
                wp[j] = reinterpret_cast<const float4*>(
                    W + (size_t)s_nodes[k] * D_MODEL);
            }

            float v[4];
            #pragma unroll
            for (int j = 0; j < 4; ++j) {
                const float4 w0 = wp[j][lane];
                const float4 w1 = wp[j][lane + 64];
                const float4 w2 = wp[j][lane + 128];
                const float4 w3 = wp[j][lane + 192];
                v[j] = x0.x * w0.x + x0.y * w0.y + x0.z * w0.z + x0.w * w0.w
                     + x1.x * w1.x + x1.y * w1.y + x1.z * w1.z + x1.w * w1.w
                     + x2.x * w2.x + x2.y * w2.y + x2.z * w2.z + x2.w * w2.w
                     + x3.x * w3.x + x3.y * w3.y + x3.z * w3.z + x3.w * w3.w;
            }

            const bool b5 = (lane & 32) != 0;
            const bool b4 = (lane & 16) != 0;
            const float t0 = b5 ? v[0] : v[2];
            const float t1 = b5 ? v[1] : v[3];
            const float r0 = __shfl_xor(t0, 32);
            const float r1 = __shfl_xor(t1, 32);
            const float a  = (b5 ? v[2] : v[0]) + r0;
            const float c  = (b5 ? v[3] : v[1]) + r1;
            const float tt = b4 ? a : c;
            const float rr = __shfl_xor(tt, 16);
            float s = (b4 ? c : a) + rr;
            s += __shfl_xor(s, 8);
            s += __shfl_xor(s, 4);
            s += __shfl_xor(s, 2);
            s += __shfl_xor(s, 1);

            const int kk = k0 + ((lane >> 4) & 3);
            const float sgn = (kk < Dmax) ? s_signs[kk] : 0.0f;
            float term = 0.0f;
            if (sgn != 0.0f) {
                const float z = sgn * s;
                term = fminf(z, 0.0f) - log1pf(expf(-fabsf(z)));
            }
            term += __shfl_xor(term, 16);
            term += __shfl_xor(term, 32);
            acc += term;
        }

        if (lane == 0) s_partial[wave] = acc;
        __syncthreads();
        if (tid == 0)
            out[b] = s_partial[0] + s_partial[1] + s_partial[2] + s_partial[3];
        __syncthreads();
    }
}

extern "C" void kernel_launch(void* const* d_in, const int* in_sizes, int n_in,
                              void* d_out, int out_size, void* d_ws, size_t ws_size,
                              hipStream_t stream) {
    const float* input      = (const float*)d_in[0];
    const float* W          = (const float*)d_in[1];
    const int*   path_nodes = (const int*)d_in[2];
    const float* path_signs = (const float*)d_in[3];
    const int*   target     = (const int*)d_in[4];
    float*       out        = (float*)d_out;

    const int B    = in_sizes[4];
    const int Dmax = in_sizes[2] / VOCAB;

    hs_kernel<<<B, 256, 0, stream>>>(input, W, path_nodes, path_signs,
                                     target, out, Dmax);
}